// Round 1
// baseline (793.850 us; speedup 1.0000x reference)
//
#include <hip/hip_runtime.h>

// Problem constants
constexpr int Bn = 16, Cd = 256, Hn = 64, Wn = 64, Kc = 1024;
constexpr int QUANT_ELEMS = Bn * Hn * Wn * Cd;   // 16777216
constexpr int LOSS_OFF = QUANT_ELEMS;            // +0 codebook_loss, +1 commitment_loss
constexpr int IDX_OFF = QUANT_ELEMS + 2;         // 65536 indices (stored as float)

// ---------------------------------------------------------------------------
// Prep 1: transpose codebook (K,C) -> cbT (C,K) so main-loop staging reads are
// coalesced along k and LDS writes are conflict-free.
__global__ __launch_bounds__(256) void transpose_cb(const float* __restrict__ cb,
                                                    float* __restrict__ cbT) {
    __shared__ float t[64][65];  // +1 pad: transpose-read banks (kk+j)%32
    const int tid = threadIdx.x;
    const int k0 = blockIdx.x * 64;   // 16 k-tiles
    const int c0 = blockIdx.y * 64;   // 4  c-tiles
    {
        const int c = tid & 63, i0 = tid >> 6;
        for (int i = i0; i < 64; i += 4)
            t[i][c] = cb[(size_t)(k0 + i) * Cd + c0 + c];   // coalesced along c
    }
    __syncthreads();
    {
        const int kk = tid & 63, j0 = tid >> 6;
        for (int j = j0; j < 64; j += 4)
            cbT[(size_t)(c0 + j) * Kc + k0 + kk] = t[kk][j]; // coalesced along k
    }
}

// Prep 2: c2[k] = ||codebook_k||^2 (one wave per code) + zero the loss slots.
__global__ __launch_bounds__(256) void c2_kernel(const float* __restrict__ cb,
                                                 float* __restrict__ c2,
                                                 float* __restrict__ out) {
    const int tid = threadIdx.x;
    const int k = blockIdx.x * 4 + (tid >> 6);
    const int lane = tid & 63;
    float s = 0.f;
    #pragma unroll
    for (int j = 0; j < 4; ++j) {
        const float v = cb[(size_t)k * Cd + lane + 64 * j];
        s += v * v;
    }
    #pragma unroll
    for (int off = 32; off >= 1; off >>= 1) s += __shfl_xor(s, off);
    if (lane == 0) c2[k] = s;
    if (blockIdx.x == 0 && tid == 0) { out[LOSS_OFF] = 0.f; out[LOSS_OFF + 1] = 0.f; }
}

// ---------------------------------------------------------------------------
// Main: per block = 64 rows (exactly one (b,h), w=0..63).
//   - stage x-tile (64 rows x 256 c) in LDS once
//   - loop 16 k-tiles of 64 codes; per tile accumulate 4x4 fp32 dots per thread
//     (16x16 threads), dist = c2[k] - 2*dot, running per-row argmin
//   - fused epilogue: gather codebook rows (L2-resident), coalesced transposed
//     quant write, loss block-reduce + atomics, index write
__global__ __launch_bounds__(256, 2) void vq_main(const float* __restrict__ x,
                                                  const float* __restrict__ cbT,
                                                  const float* __restrict__ c2,
                                                  float* __restrict__ out) {
    __shared__ float xs[Cd][Wn];   // 64 KB: xs[c][w]
    __shared__ float cs[32][64];   // 8 KB:  cs[c][kk], stride 64 -> 2-way banks only
    __shared__ int   idx_s[Wn];
    __shared__ float red[4];

    const int tid = threadIdx.x;
    const int bh = blockIdx.x;            // 1024 blocks
    const int b = bh >> 6, h = bh & 63;
    const float* xbase = x + ((size_t)b * Cd * Hn + h) * Wn;  // x[b][c][h][w] = xbase[c*4096 + w]

    // Stage x-tile: float4, coalesced 256B per c-row
    {
        const int w4 = (tid & 15) * 4;
        const int cq = tid >> 4;
        #pragma unroll
        for (int it = 0; it < 16; ++it) {
            const int c = cq + it * 16;
            const float4 v = *(const float4*)(xbase + (size_t)c * 4096 + w4);
            *(float4*)&xs[c][w4] = v;
        }
    }

    const int tx = tid & 15, ty = tid >> 4;   // tx->codes, ty->rows(w)
    float bestd[4];
    int   besti[4];
    #pragma unroll
    for (int r = 0; r < 4; ++r) { bestd[r] = 3.4e38f; besti[r] = 0; }

    for (int k0 = 0; k0 < Kc; k0 += 64) {
        float acc[4][4];
        #pragma unroll
        for (int r = 0; r < 4; ++r)
            #pragma unroll
            for (int q = 0; q < 4; ++q) acc[r][q] = 0.f;

        for (int cc = 0; cc < Cd; cc += 32) {
            __syncthreads();  // protect cs (and xs on first pass)
            {   // stage cs[c][kk] from cbT: coalesced along k, LDS banks kk%32 (2-way, free)
                const int kk = tid & 63, cq = tid >> 6;
                #pragma unroll
                for (int it = 0; it < 8; ++it) {
                    const int c = cq + it * 4;
                    cs[c][kk] = cbT[(size_t)(cc + c) * Kc + k0 + kk];
                }
            }
            __syncthreads();
            #pragma unroll
            for (int i = 0; i < 32; ++i) {
                const float4 a  = *(const float4*)&xs[cc + i][ty * 4];  // b128, 2-way banks
                const float4 bv = *(const float4*)&cs[i][tx * 4];       // b128, 2-way banks
                const float av[4] = {a.x, a.y, a.z, a.w};
                const float bb[4] = {bv.x, bv.y, bv.z, bv.w};
                #pragma unroll
                for (int r = 0; r < 4; ++r)
                    #pragma unroll
                    for (int q = 0; q < 4; ++q) acc[r][q] += av[r] * bb[q];
            }
        }
        // dist = c2 - 2*dot (x^2 row-constant: argmin unchanged); k ascending -> ties keep lowest k
        #pragma unroll
        for (int q = 0; q < 4; ++q) {
            const int k = k0 + tx * 4 + q;
            const float ck = c2[k];
            #pragma unroll
            for (int r = 0; r < 4; ++r) {
                const float d = ck - 2.0f * acc[r][q];
                if (d < bestd[r]) { bestd[r] = d; besti[r] = k; }
            }
        }
    }

    // Argmin reduce across the 16 tx lanes sharing each row group (lanes are contiguous)
    #pragma unroll
    for (int off = 1; off < 16; off <<= 1) {
        #pragma unroll
        for (int r = 0; r < 4; ++r) {
            const float od = __shfl_xor(bestd[r], off);
            const int   oi = __shfl_xor(besti[r], off);
            if (od < bestd[r] || (od == bestd[r] && oi < besti[r])) { bestd[r] = od; besti[r] = oi; }
        }
    }
    if (tx == 0) {
        #pragma unroll
        for (int r = 0; r < 4; ++r) idx_s[ty * 4 + r] = besti[r];
    }
    __syncthreads();

    // Epilogue: gather + transposed coalesced write + loss
    const int w = tid & 63;
    const int cq2 = tid >> 6;
    const int myidx = idx_s[w];
    float* obase = out + ((size_t)b * Cd * Hn + h) * Wn;
    float lsum = 0.f;
    for (int c = cq2; c < Cd; c += 4) {
        const float qv = cbT[(size_t)c * Kc + myidx];  // scattered in 4KB row, L2-resident
        const float xv = xs[c][w];
        const float dd = qv - xv;
        lsum += dd * dd;
        obase[(size_t)c * 4096 + w] = qv;              // coalesced along w
    }
    if (tid < 64) out[IDX_OFF + (size_t)bh * 64 + tid] = (float)idx_s[tid];

    #pragma unroll
    for (int off = 32; off >= 1; off >>= 1) lsum += __shfl_xor(lsum, off);
    if ((tid & 63) == 0) red[tid >> 6] = lsum;
    __syncthreads();
    if (tid == 0) {
        const float s = (red[0] + red[1] + red[2] + red[3]) * (1.0f / 16777216.0f);
        atomicAdd(out + LOSS_OFF, s);      // codebook_loss
        atomicAdd(out + LOSS_OFF + 1, s);  // commitment_loss (identical value)
    }
}

// ---------------------------------------------------------------------------
extern "C" void kernel_launch(void* const* d_in, const int* in_sizes, int n_in,
                              void* d_out, int out_size, void* d_ws, size_t ws_size,
                              hipStream_t stream) {
    const float* x  = (const float*)d_in[0];   // (16,256,64,64)
    const float* cb = (const float*)d_in[1];   // (1024,256)
    float* out = (float*)d_out;
    float* cbT = (float*)d_ws;                 // 1M floats
    float* c2  = cbT + (size_t)Cd * Kc;        // 1024 floats

    transpose_cb<<<dim3(16, 4), 256, 0, stream>>>(cb, cbT);
    c2_kernel<<<256, 256, 0, stream>>>(cb, c2, out);
    vq_main<<<Bn * Hn, 256, 0, stream>>>(x, cbT, c2, out);
}